// Round 6
// baseline (249.647 us; speedup 1.0000x reference)
//
#include <hip/hip_runtime.h>
#include <math.h>

#define B_     4
#define N_     2048
#define F_     256
#define H_     4
#define DH     64
#define BN     8192
#define SP     72    // padded f16 stride for P slab
#define SPW    264   // padded f16 stride for out-kernel ctx rows

#define QSCALE 0.18033688011112042f   // 0.125 * log2(e)
#define CLIP   14.426950408889634f    // 10 * log2(e)

typedef _Float16 f16;
typedef _Float16 half8  __attribute__((ext_vector_type(8)));
typedef _Float16 half4v __attribute__((ext_vector_type(4)));
typedef float    floatx4 __attribute__((ext_vector_type(4)));
typedef unsigned long long u64;

__device__ __forceinline__ half8 cvt8(float4 a, float4 b) {
    half8 h;
    h[0] = (f16)a.x; h[1] = (f16)a.y; h[2] = (f16)a.z; h[3] = (f16)a.w;
    h[4] = (f16)b.x; h[5] = (f16)b.y; h[6] = (f16)b.z; h[7] = (f16)b.w;
    return h;
}

// ---------------------------------------------------------------------------
// Kernel 0a: pack adj into 1 bit/key.
// ---------------------------------------------------------------------------
__global__ __launch_bounds__(256) void pack_adj(
    const int* __restrict__ adj, u64* __restrict__ P)
{
    const int row   = blockIdx.x >> 3;
    const int chunk = blockIdx.x & 7;
    const int wave  = threadIdx.x >> 6, lane = threadIdx.x & 63;
    const int key   = chunk * 256 + wave * 64 + lane;
    u64 m = __ballot(adj[(size_t)row * N_ + key] != 0);
    if (lane == 0) P[(size_t)row * 32 + chunk * 4 + wave] = m;
}

// ---------------------------------------------------------------------------
// Kernel 0b: Wo fp32 -> f16 (natural [o][f] layout; B-operand wants rows).
// ---------------------------------------------------------------------------
__global__ __launch_bounds__(256) void cvt_wo(
    const float* __restrict__ Wo, f16* __restrict__ Woh)
{
    const int idx = (blockIdx.x * 256 + threadIdx.x) * 4;
    float4 v = *(const float4*)(Wo + idx);
    half4v h; h[0] = (f16)v.x; h[1] = (f16)v.y; h[2] = (f16)v.z; h[3] = (f16)v.w;
    *(half4v*)(Woh + idx) = h;
}

// ---------------------------------------------------------------------------
// Kernel 1: QKV projection via MFMA (fused fp32->f16).  Q is pre-scaled by
// 0.125*log2(e) so attention needs no per-score multiply.
// ---------------------------------------------------------------------------
__global__ __launch_bounds__(256) void proj_mfma(
    const float* __restrict__ x,
    const float* __restrict__ Wq, const float* __restrict__ Wk, const float* __restrict__ Wv,
    const float* __restrict__ bq, const float* __restrict__ bk, const float* __restrict__ bv,
    f16* __restrict__ Qh, f16* __restrict__ Kh, f16* __restrict__ Vt)
{
    const int which = blockIdx.z;
    const float* W    = which == 0 ? Wq : which == 1 ? Wk : Wv;
    const float* bias = which == 0 ? bq : which == 1 ? bk : bv;

    const int r0 = blockIdx.x * 64;
    const int hy = blockIdx.y;
    const int c0 = hy * 64;
    const int tid  = threadIdx.x;
    const int wave = tid >> 6, lane = tid & 63;
    const int quad = lane >> 4, l16 = lane & 15;
    const int row = tid >> 2, seg = tid & 3;

    __shared__ f16 xs[64 * SP];
    __shared__ f16 wsm[64 * SP];

    floatx4 zz = {0.f, 0.f, 0.f, 0.f};
    floatx4 acc[4] = {zz, zz, zz, zz};

    for (int f0 = 0; f0 < F_; f0 += 64) {
        const float* xsrc = x + (size_t)(r0 + row) * F_ + f0 + seg * 16;
        const float* wsrc = W + (size_t)(c0 + row) * F_ + f0 + seg * 16;
        float4 xa0 = *(const float4*)(xsrc + 0), xa1 = *(const float4*)(xsrc + 4);
        float4 xa2 = *(const float4*)(xsrc + 8), xa3 = *(const float4*)(xsrc + 12);
        float4 wa0 = *(const float4*)(wsrc + 0), wa1 = *(const float4*)(wsrc + 4);
        float4 wa2 = *(const float4*)(wsrc + 8), wa3 = *(const float4*)(wsrc + 12);
        __syncthreads();
        *(half8*)&xs[row * SP + seg * 16]      = cvt8(xa0, xa1);
        *(half8*)&xs[row * SP + seg * 16 + 8]  = cvt8(xa2, xa3);
        *(half8*)&wsm[row * SP + seg * 16]     = cvt8(wa0, wa1);
        *(half8*)&wsm[row * SP + seg * 16 + 8] = cvt8(wa2, wa3);
        __syncthreads();
#pragma unroll
        for (int s = 0; s < 2; s++) {
            half8 af = *(const half8*)&xs[(wave * 16 + l16) * SP + s * 32 + quad * 8];
#pragma unroll
            for (int ot = 0; ot < 4; ot++) {
                half8 bf = *(const half8*)&wsm[(ot * 16 + l16) * SP + s * 32 + quad * 8];
                acc[ot] = __builtin_amdgcn_mfma_f32_16x16x32_f16(af, bf, acc[ot], 0, 0, 0);
            }
        }
    }

    const int bb = r0 >> 11, nn0 = r0 & (N_ - 1);

    if (which == 2) {
#pragma unroll
        for (int ot = 0; ot < 4; ot++) {
            const float bv_ = bias[c0 + ot * 16 + l16];
            half4v h4;
#pragma unroll
            for (int r = 0; r < 4; r++) h4[r] = (f16)(acc[ot][r] + bv_);
            *(half4v*)(Vt + (((size_t)bb * H_ + hy) * DH + ot * 16 + l16) * N_
                          + nn0 + wave * 16 + quad * 4) = h4;
        }
    } else {
        const float scl = (which == 0) ? QSCALE : 1.0f;
        f16* dst = which == 0 ? Qh : Kh;
        __syncthreads();
        f16* outb = xs;   // reuse
#pragma unroll
        for (int ot = 0; ot < 4; ot++) {
            const float bv_ = bias[c0 + ot * 16 + l16];
#pragma unroll
            for (int r = 0; r < 4; r++)
                outb[(wave * 16 + quad * 4 + r) * SP + ot * 16 + l16] =
                    (f16)((acc[ot][r] + bv_) * scl);
        }
        __syncthreads();
        f16* g = dst + (((size_t)bb * H_ + hy) * N_ + nn0 + row) * DH + seg * 16;
        *(float4*)(g)     = *(const float4*)&outb[row * SP + seg * 16];
        *(float4*)(g + 8) = *(const float4*)&outb[row * SP + seg * 16 + 8];
    }
}

// ---------------------------------------------------------------------------
// Kernel 2: barrier-free MFMA attention.  K/V/Q fragments loaded DIRECTLY
// from global (fragment addressing == contiguous 16B rows); only the
// wave-private P round-trip uses LDS.  No __syncthreads anywhere.
// ---------------------------------------------------------------------------
__global__ __launch_bounds__(256) void attn_mfma(
    const f16* __restrict__ Qh, const f16* __restrict__ Kh,
    const f16* __restrict__ Vt, const u64* __restrict__ Padj,
    f16* __restrict__ CTXP)
{
    const int nt = blockIdx.x & 31;
    const int sp = blockIdx.x >> 5;        // split 0..3 (2 chunks each)
    const int qb = nt * 64;
    const int h  = blockIdx.y;
    const int b  = blockIdx.z;
    const int bh = b * H_ + h;
    const int tid  = threadIdx.x;
    const int wave = tid >> 6, lane = tid & 63;
    const int quad = lane >> 4, l16 = lane & 15;

    __shared__ f16 Ps[4 * 16 * SP];
    f16* Psw = Ps + wave * 16 * SP;

    // Q fragments direct from global (held all kernel)
    const f16* qbase = Qh + ((size_t)bh * N_ + qb + wave * 16 + l16) * DH + quad * 8;
    const half8 qf0 = *(const half8*)(qbase);
    const half8 qf1 = *(const half8*)(qbase + 32);

    const int qglob = qb + wave * 16 + l16;
    const u64* arow = Padj + (size_t)qglob * 32;

    floatx4 zz = {0.f, 0.f, 0.f, 0.f};
    floatx4 ctx_tot[4] = {zz, zz, zz, zz};

    for (int ci = 0; ci < 2; ci++) {
        const int c = sp * 2 + ci;
        floatx4 ctx_ch[4] = {zz, zz, zz, zz};
        float rs_ch = 0.f;

        for (int kt = 0; kt < 4; kt++) {
            const int k0 = c * 256 + kt * 64;
            const u64 aw = arow[k0 >> 6];
            const f16* kb = Kh + ((size_t)bh * N_ + k0 + l16) * DH + quad * 8;
            const f16* vb = Vt + ((size_t)bh * DH + l16) * N_ + k0 + quad * 8;

            float rs = 0.f;
#pragma unroll
            for (int m = 0; m < 4; m++) {
                half8 a0 = *(const half8*)(kb + m * 16 * DH);
                half8 a1 = *(const half8*)(kb + m * 16 * DH + 32);
                floatx4 sacc = zz;
                sacc = __builtin_amdgcn_mfma_f32_16x16x32_f16(a0, qf0, sacc, 0, 0, 0);
                sacc = __builtin_amdgcn_mfma_f32_16x16x32_f16(a1, qf1, sacc, 0, 0, 0);
                const unsigned int nib = (unsigned int)(aw >> (m * 16 + quad * 4)) & 0xFu;
                half4v pv;
#pragma unroll
                for (int r = 0; r < 4; r++) {
                    float sv = fminf(fmaxf(sacc[r], -CLIP), CLIP);
                    sv = ((nib >> r) & 1u) ? sv : -CLIP;
                    const float ev = __builtin_amdgcn_exp2f(sv);
                    rs += ev;
                    pv[r] = (f16)ev;
                }
                *(half4v*)&Psw[l16 * SP + m * 16 + quad * 4] = pv;
            }
            rs += __shfl_xor(rs, 16);
            rs += __shfl_xor(rs, 32);
            rs_ch += rs;

            const half8 p0 = *(const half8*)&Psw[l16 * SP + quad * 8];
            const half8 p1 = *(const half8*)&Psw[l16 * SP + 32 + quad * 8];
#pragma unroll
            for (int m = 0; m < 4; m++) {
                half8 va  = *(const half8*)(vb + (size_t)(m * 16) * N_);
                half8 vb8 = *(const half8*)(vb + (size_t)(m * 16) * N_ + 32);
                ctx_ch[m] = __builtin_amdgcn_mfma_f32_16x16x32_f16(va,  p0, ctx_ch[m], 0, 0, 0);
                ctx_ch[m] = __builtin_amdgcn_mfma_f32_16x16x32_f16(vb8, p1, ctx_ch[m], 0, 0, 0);
            }
        }

        const float inv = 1.0f / rs_ch;
#pragma unroll
        for (int m = 0; m < 4; m++)
#pragma unroll
            for (int r = 0; r < 4; r++)
                ctx_tot[m][r] += ctx_ch[m][r] * inv;
    }

    f16* dst = CTXP + (((size_t)sp * B_ + b) * N_ + qglob) * F_ + h * DH;
#pragma unroll
    for (int m = 0; m < 4; m++) {
        half4v h4;
#pragma unroll
        for (int r = 0; r < 4; r++) h4[r] = (f16)ctx_tot[m][r];
        *(half4v*)&dst[m * 16 + quad * 4] = h4;
    }
}

// ---------------------------------------------------------------------------
// Kernel 3: fused [sum 4 partials] + [ctx @ Wo^T + bo + x] + LayerNorm.
// Block = 16 rows x 256 cols; 4 waves, wave w owns cols w*64..w*64+63.
// ctx staged once (f16, summed from partials); Wo B-frags direct from global.
// ---------------------------------------------------------------------------
__global__ __launch_bounds__(256) void out_mfma(
    const f16* __restrict__ CTXP, const float* __restrict__ x,
    const f16* __restrict__ Woh, const float* __restrict__ bo,
    const float* __restrict__ gamma, const float* __restrict__ beta,
    float* __restrict__ out)
{
    const int n0 = blockIdx.x * 16;
    const int tid  = threadIdx.x;
    const int wave = tid >> 6, lane = tid & 63;
    const int quad = lane >> 4, l16 = lane & 15;

    __shared__ f16 cs[16 * SPW];
    __shared__ float red0[4][16], red1[4][16];

    {   // stage ctx rows: sum the 4 f16 split-partials in fp32, store f16
        const int row = tid >> 4, c0 = (tid & 15) * 16;
        const size_t S = (size_t)BN * F_;
        const f16* p = CTXP + (size_t)(n0 + row) * F_ + c0;
#pragma unroll
        for (int g = 0; g < 2; g++) {
            half8 s0 = *(const half8*)(p + g * 8);
            half8 s1 = *(const half8*)(p + S + g * 8);
            half8 s2 = *(const half8*)(p + 2 * S + g * 8);
            half8 s3 = *(const half8*)(p + 3 * S + g * 8);
            half8 o;
#pragma unroll
            for (int e = 0; e < 8; e++)
                o[e] = (f16)(((float)s0[e] + (float)s1[e]) + ((float)s2[e] + (float)s3[e]));
            *(half8*)&cs[row * SPW + c0 + g * 8] = o;
        }
    }
    __syncthreads();

    floatx4 zz = {0.f, 0.f, 0.f, 0.f};
    floatx4 acc[4] = {zz, zz, zz, zz};

#pragma unroll
    for (int f0 = 0; f0 < F_; f0 += 64) {
        half8 a0 = *(const half8*)&cs[l16 * SPW + f0 + quad * 8];
        half8 a1 = *(const half8*)&cs[l16 * SPW + f0 + 32 + quad * 8];
#pragma unroll
        for (int ot = 0; ot < 4; ot++) {
            const f16* wrow = Woh + (size_t)(wave * 64 + ot * 16 + l16) * F_ + f0 + quad * 8;
            half8 b0 = *(const half8*)(wrow);
            half8 b1 = *(const half8*)(wrow + 32);
            acc[ot] = __builtin_amdgcn_mfma_f32_16x16x32_f16(a0, b0, acc[ot], 0, 0, 0);
            acc[ot] = __builtin_amdgcn_mfma_f32_16x16x32_f16(a1, b1, acc[ot], 0, 0, 0);
        }
    }

    // bias + residual (acc becomes pre-LN value)
#pragma unroll
    for (int ot = 0; ot < 4; ot++) {
        const int o = wave * 64 + ot * 16 + l16;
        const float bo_ = bo[o];
#pragma unroll
        for (int r = 0; r < 4; r++)
            acc[ot][r] += bo_ + x[(size_t)(n0 + quad * 4 + r) * F_ + o];
    }

    // per-row partial sums over this wave's 64 cols
#pragma unroll
    for (int r = 0; r < 4; r++) {
        float s = (acc[0][r] + acc[1][r]) + (acc[2][r] + acc[3][r]);
        float q = (acc[0][r] * acc[0][r] + acc[1][r] * acc[1][r]) +
                  (acc[2][r] * acc[2][r] + acc[3][r] * acc[3][r]);
        s += __shfl_xor(s, 1); q += __shfl_xor(q, 1);
        s += __shfl_xor(s, 2); q += __shfl_xor(q, 2);
        s += __shfl_xor(s, 4); q += __shfl_xor(q, 4);
        s += __shfl_xor(s, 8); q += __shfl_xor(q, 8);
        if (l16 == 0) { red0[wave][quad * 4 + r] = s; red1[wave][quad * 4 + r] = q; }
    }
    __syncthreads();

#pragma unroll
    for (int r = 0; r < 4; r++) {
        const int rr = quad * 4 + r;
        const float S  = (red0[0][rr] + red0[1][rr]) + (red0[2][rr] + red0[3][rr]);
        const float Q2 = (red1[0][rr] + red1[1][rr]) + (red1[2][rr] + red1[3][rr]);
        const float mu  = S * (1.0f / F_);
        const float var = Q2 * (1.0f / F_) - mu * mu;
        const float inv = rsqrtf(var + 1e-5f);
#pragma unroll
        for (int ot = 0; ot < 4; ot++) {
            const int o = wave * 64 + ot * 16 + l16;
            out[(size_t)(n0 + rr) * F_ + o] =
                (acc[ot][r] - mu) * inv * gamma[o] + beta[o];
        }
    }
}

// ---------------------------------------------------------------------------
extern "C" void kernel_launch(void* const* d_in, const int* in_sizes, int n_in,
                              void* d_out, int out_size, void* d_ws, size_t ws_size,
                              hipStream_t stream)
{
    const float* x     = (const float*)d_in[0];
    const int*   adj   = (const int*)  d_in[1];
    const float* Wq    = (const float*)d_in[2];
    const float* bq    = (const float*)d_in[3];
    const float* Wk    = (const float*)d_in[4];
    const float* bk    = (const float*)d_in[5];
    const float* Wv    = (const float*)d_in[6];
    const float* bv    = (const float*)d_in[7];
    const float* Wo    = (const float*)d_in[8];
    const float* bo    = (const float*)d_in[9];
    const float* gamma = (const float*)d_in[10];
    const float* beta  = (const float*)d_in[11];
    float* out = (float*)d_out;

    float* ws = (float*)d_ws;
    f16*   CTXP = (f16*)(ws);                       // 8M halves = 4,194,304 fl
    f16*   Qh   = (f16*)(ws + 4194304);             // 2M halves = 1,048,576 fl
    f16*   Kh   = (f16*)(ws + 5242880);
    f16*   Vt   = (f16*)(ws + 6291456);
    u64*   Padj = (u64*)(ws + 7340032);             // 512 KB = 131,072 fl
    f16*   Woh  = (f16*)(ws + 7471104);             // 64K halves = 32,768 fl

    hipLaunchKernelGGL(pack_adj, dim3(N_ * 8), dim3(256), 0, stream, adj, Padj);
    hipLaunchKernelGGL(cvt_wo, dim3(64), dim3(256), 0, stream, Wo, Woh);
    hipLaunchKernelGGL(proj_mfma, dim3(BN / 64, H_, 3), dim3(256), 0, stream,
                       x, Wq, Wk, Wv, bq, bk, bv, Qh, Kh, Vt);
    hipLaunchKernelGGL(attn_mfma, dim3(128, H_, B_), dim3(256), 0, stream,
                       Qh, Kh, Vt, Padj, CTXP);
    hipLaunchKernelGGL(out_mfma, dim3(BN / 16), dim3(256), 0, stream,
                       CTXP, x, Woh, bo, gamma, beta, out);
}

// Round 7
// 159.945 us; speedup vs baseline: 1.5608x; 1.5608x over previous
//
#include <hip/hip_runtime.h>
#include <math.h>

#define B_     4
#define N_     2048
#define F_     256
#define H_     4
#define DH     64
#define BN     8192
#define SP     72    // padded f16 stride (64 + 8) -> 144 B, 16B-aligned
#define SPW    264   // padded f16 stride for out-kernel ctx rows

#define QSCALE 0.18033688011112042f   // 0.125 * log2(e)
#define CLIP   14.426950408889634f    // 10 * log2(e)

typedef _Float16 f16;
typedef _Float16 half8  __attribute__((ext_vector_type(8)));
typedef _Float16 half4v __attribute__((ext_vector_type(4)));
typedef float    floatx4 __attribute__((ext_vector_type(4)));
typedef unsigned long long u64;

__device__ __forceinline__ half8 cvt8(float4 a, float4 b) {
    half8 h;
    h[0] = (f16)a.x; h[1] = (f16)a.y; h[2] = (f16)a.z; h[3] = (f16)a.w;
    h[4] = (f16)b.x; h[5] = (f16)b.y; h[6] = (f16)b.z; h[7] = (f16)b.w;
    return h;
}

// ---------------------------------------------------------------------------
// Kernel 0a: pack adj into 1 bit/key.
// ---------------------------------------------------------------------------
__global__ __launch_bounds__(256) void pack_adj(
    const int* __restrict__ adj, u64* __restrict__ P)
{
    const int row   = blockIdx.x >> 3;
    const int chunk = blockIdx.x & 7;
    const int wave  = threadIdx.x >> 6, lane = threadIdx.x & 63;
    const int key   = chunk * 256 + wave * 64 + lane;
    u64 m = __ballot(adj[(size_t)row * N_ + key] != 0);
    if (lane == 0) P[(size_t)row * 32 + chunk * 4 + wave] = m;
}

// ---------------------------------------------------------------------------
// Kernel 0b: Wo fp32 -> f16 (natural [o][f] layout).
// ---------------------------------------------------------------------------
__global__ __launch_bounds__(256) void cvt_wo(
    const float* __restrict__ Wo, f16* __restrict__ Woh)
{
    const int idx = (blockIdx.x * 256 + threadIdx.x) * 4;
    float4 v = *(const float4*)(Wo + idx);
    half4v h; h[0] = (f16)v.x; h[1] = (f16)v.y; h[2] = (f16)v.z; h[3] = (f16)v.w;
    *(half4v*)(Woh + idx) = h;
}

// ---------------------------------------------------------------------------
// Kernel 1: QKV projection via MFMA (fused fp32->f16).  Q pre-scaled by
// 0.125*log2(e) so attention uses raw exp2.
// ---------------------------------------------------------------------------
__global__ __launch_bounds__(256) void proj_mfma(
    const float* __restrict__ x,
    const float* __restrict__ Wq, const float* __restrict__ Wk, const float* __restrict__ Wv,
    const float* __restrict__ bq, const float* __restrict__ bk, const float* __restrict__ bv,
    f16* __restrict__ Qh, f16* __restrict__ Kh, f16* __restrict__ Vt)
{
    const int which = blockIdx.z;
    const float* W    = which == 0 ? Wq : which == 1 ? Wk : Wv;
    const float* bias = which == 0 ? bq : which == 1 ? bk : bv;

    const int r0 = blockIdx.x * 64;
    const int hy = blockIdx.y;
    const int c0 = hy * 64;
    const int tid  = threadIdx.x;
    const int wave = tid >> 6, lane = tid & 63;
    const int quad = lane >> 4, l16 = lane & 15;
    const int row = tid >> 2, seg = tid & 3;

    __shared__ f16 xs[64 * SP];
    __shared__ f16 wsm[64 * SP];

    floatx4 zz = {0.f, 0.f, 0.f, 0.f};
    floatx4 acc[4] = {zz, zz, zz, zz};

    for (int f0 = 0; f0 < F_; f0 += 64) {
        const float* xsrc = x + (size_t)(r0 + row) * F_ + f0 + seg * 16;
        const float* wsrc = W + (size_t)(c0 + row) * F_ + f0 + seg * 16;
        float4 xa0 = *(const float4*)(xsrc + 0), xa1 = *(const float4*)(xsrc + 4);
        float4 xa2 = *(const float4*)(xsrc + 8), xa3 = *(const float4*)(xsrc + 12);
        float4 wa0 = *(const float4*)(wsrc + 0), wa1 = *(const float4*)(wsrc + 4);
        float4 wa2 = *(const float4*)(wsrc + 8), wa3 = *(const float4*)(wsrc + 12);
        __syncthreads();
        *(half8*)&xs[row * SP + seg * 16]      = cvt8(xa0, xa1);
        *(half8*)&xs[row * SP + seg * 16 + 8]  = cvt8(xa2, xa3);
        *(half8*)&wsm[row * SP + seg * 16]     = cvt8(wa0, wa1);
        *(half8*)&wsm[row * SP + seg * 16 + 8] = cvt8(wa2, wa3);
        __syncthreads();
#pragma unroll
        for (int s = 0; s < 2; s++) {
            half8 af = *(const half8*)&xs[(wave * 16 + l16) * SP + s * 32 + quad * 8];
#pragma unroll
            for (int ot = 0; ot < 4; ot++) {
                half8 bf = *(const half8*)&wsm[(ot * 16 + l16) * SP + s * 32 + quad * 8];
                acc[ot] = __builtin_amdgcn_mfma_f32_16x16x32_f16(af, bf, acc[ot], 0, 0, 0);
            }
        }
    }

    const int bb = r0 >> 11, nn0 = r0 & (N_ - 1);

    if (which == 2) {
#pragma unroll
        for (int ot = 0; ot < 4; ot++) {
            const float bv_ = bias[c0 + ot * 16 + l16];
            half4v h4;
#pragma unroll
            for (int r = 0; r < 4; r++) h4[r] = (f16)(acc[ot][r] + bv_);
            *(half4v*)(Vt + (((size_t)bb * H_ + hy) * DH + ot * 16 + l16) * N_
                          + nn0 + wave * 16 + quad * 4) = h4;
        }
    } else {
        const float scl = (which == 0) ? QSCALE : 1.0f;
        f16* dst = which == 0 ? Qh : Kh;
        __syncthreads();
        f16* outb = xs;   // reuse
#pragma unroll
        for (int ot = 0; ot < 4; ot++) {
            const float bv_ = bias[c0 + ot * 16 + l16];
#pragma unroll
            for (int r = 0; r < 4; r++)
                outb[(wave * 16 + quad * 4 + r) * SP + ot * 16 + l16] =
                    (f16)((acc[ot][r] + bv_) * scl);
        }
        __syncthreads();
        f16* g = dst + (((size_t)bb * H_ + hy) * N_ + nn0 + row) * DH + seg * 16;
        *(float4*)(g)     = *(const float4*)&outb[row * SP + seg * 16];
        *(float4*)(g + 8) = *(const float4*)&outb[row * SP + seg * 16 + 8];
    }
}

// ---------------------------------------------------------------------------
// Kernel 2: MFMA chunked attention (LDS-staged, chunk-split x4) — the
// proven R5 structure; score math uses pre-scaled Q + exp2 + packed mask.
// ---------------------------------------------------------------------------
__global__ __launch_bounds__(256) void attn_mfma(
    const f16* __restrict__ Qh, const f16* __restrict__ Kh,
    const f16* __restrict__ Vt, const u64* __restrict__ Padj,
    f16* __restrict__ CTXP)
{
    const int nt = blockIdx.x & 31;
    const int sp = blockIdx.x >> 5;        // split 0..3 (2 chunks each)
    const int qb = nt * 64;
    const int h  = blockIdx.y;
    const int b  = blockIdx.z;
    const int bh = b * H_ + h;
    const int tid  = threadIdx.x;
    const int wave = tid >> 6, lane = tid & 63;
    const int quad = lane >> 4, l16 = lane & 15;
    const int row = tid >> 2, seg = tid & 3;

    __shared__ f16 QPs[64 * SP];   // Q stage, then per-wave P slabs
    __shared__ f16 Ks[64 * SP];
    __shared__ f16 Vs[64 * SP];    // [d][key]

    {   // stage Q tile [q][dh]
        const f16* src = Qh + ((size_t)bh * N_ + qb + row) * DH + seg * 16;
        *(float4*)&QPs[row * SP + seg * 16]     = *(const float4*)(src);
        *(float4*)&QPs[row * SP + seg * 16 + 8] = *(const float4*)(src + 8);
    }
    __syncthreads();
    const half8 qf0 = *(const half8*)&QPs[(wave * 16 + l16) * SP + quad * 8];
    const half8 qf1 = *(const half8*)&QPs[(wave * 16 + l16) * SP + 32 + quad * 8];
    f16* Ps = QPs + wave * 16 * SP;   // wave-private 16 x SP

    const int qglob = qb + wave * 16 + l16;
    const u64* arow = Padj + (size_t)qglob * 32;

    floatx4 zz = {0.f, 0.f, 0.f, 0.f};
    floatx4 ctx_tot[4] = {zz, zz, zz, zz};

    for (int ci = 0; ci < 2; ci++) {
        const int c = sp * 2 + ci;
        floatx4 ctx_ch[4] = {zz, zz, zz, zz};
        float rs_ch = 0.f;

        for (int kt = 0; kt < 4; kt++) {
            const int k0 = c * 256 + kt * 64;
            const f16* ksrc = Kh + ((size_t)bh * N_ + k0 + row) * DH + seg * 16;
            const f16* vsrc = Vt + ((size_t)bh * DH + row) * N_ + k0 + seg * 16;
            float4 ka0 = *(const float4*)(ksrc), ka1 = *(const float4*)(ksrc + 8);
            float4 va0 = *(const float4*)(vsrc), va1 = *(const float4*)(vsrc + 8);
            __syncthreads();
            *(float4*)&Ks[row * SP + seg * 16]     = ka0;
            *(float4*)&Ks[row * SP + seg * 16 + 8] = ka1;
            *(float4*)&Vs[row * SP + seg * 16]     = va0;
            *(float4*)&Vs[row * SP + seg * 16 + 8] = va1;
            __syncthreads();

            const u64 aw = arow[k0 >> 6];
            float rs = 0.f;
#pragma unroll
            for (int m = 0; m < 4; m++) {
                floatx4 sacc = zz;
                half8 a0 = *(const half8*)&Ks[(m * 16 + l16) * SP + quad * 8];
                half8 a1 = *(const half8*)&Ks[(m * 16 + l16) * SP + 32 + quad * 8];
                sacc = __builtin_amdgcn_mfma_f32_16x16x32_f16(a0, qf0, sacc, 0, 0, 0);
                sacc = __builtin_amdgcn_mfma_f32_16x16x32_f16(a1, qf1, sacc, 0, 0, 0);
                const unsigned int nib = (unsigned int)(aw >> (m * 16 + quad * 4)) & 0xFu;
                half4v pv;
#pragma unroll
                for (int r = 0; r < 4; r++) {
                    float sv = fminf(fmaxf(sacc[r], -CLIP), CLIP);
                    sv = ((nib >> r) & 1u) ? sv : -CLIP;
                    const float ev = __builtin_amdgcn_exp2f(sv);
                    rs += ev;
                    pv[r] = (f16)ev;
                }
                *(half4v*)&Ps[l16 * SP + m * 16 + quad * 4] = pv;
            }
            rs += __shfl_xor(rs, 16);
            rs += __shfl_xor(rs, 32);
            rs_ch += rs;

            const half8 p0 = *(const half8*)&Ps[l16 * SP + quad * 8];
            const half8 p1 = *(const half8*)&Ps[l16 * SP + 32 + quad * 8];
#pragma unroll
            for (int m = 0; m < 4; m++) {
                half8 va = *(const half8*)&Vs[(m * 16 + l16) * SP + quad * 8];
                half8 vb = *(const half8*)&Vs[(m * 16 + l16) * SP + 32 + quad * 8];
                ctx_ch[m] = __builtin_amdgcn_mfma_f32_16x16x32_f16(va, p0, ctx_ch[m], 0, 0, 0);
                ctx_ch[m] = __builtin_amdgcn_mfma_f32_16x16x32_f16(vb, p1, ctx_ch[m], 0, 0, 0);
            }
        }

        const float inv = 1.0f / rs_ch;
#pragma unroll
        for (int m = 0; m < 4; m++)
#pragma unroll
            for (int r = 0; r < 4; r++)
                ctx_tot[m][r] += ctx_ch[m][r] * inv;
    }

    f16* dst = CTXP + (((size_t)sp * B_ + b) * N_ + qglob) * F_ + h * DH;
#pragma unroll
    for (int m = 0; m < 4; m++) {
        half4v h4;
#pragma unroll
        for (int r = 0; r < 4; r++) h4[r] = (f16)ctx_tot[m][r];
        *(half4v*)&dst[m * 16 + quad * 4] = h4;
    }
}

// ---------------------------------------------------------------------------
// Kernel 3: fused [sum 4 partials] + [ctx @ Wo^T + bo + x] + LayerNorm.
// Block = 16 rows x 256 cols.  Wo f0-slices staged in LDS (256 x 64, padded).
// ---------------------------------------------------------------------------
__global__ __launch_bounds__(256) void out_mfma(
    const f16* __restrict__ CTXP, const float* __restrict__ x,
    const f16* __restrict__ Woh, const float* __restrict__ bo,
    const float* __restrict__ gamma, const float* __restrict__ beta,
    float* __restrict__ out)
{
    const int n0 = blockIdx.x * 16;
    const int tid  = threadIdx.x;
    const int wave = tid >> 6, lane = tid & 63;
    const int quad = lane >> 4, l16 = lane & 15;
    const int wrow = tid >> 2, wseg = tid & 3;

    __shared__ f16 cs[16 * SPW];
    __shared__ f16 wtile[256 * SP];
    __shared__ float red0[4][16], red1[4][16];

    {   // stage ctx rows: sum 4 f16 split-partials in fp32, store f16
        const int row = tid >> 4, c0 = (tid & 15) * 16;
        const size_t S = (size_t)BN * F_;
        const f16* p = CTXP + (size_t)(n0 + row) * F_ + c0;
#pragma unroll
        for (int g = 0; g < 2; g++) {
            half8 s0 = *(const half8*)(p + g * 8);
            half8 s1 = *(const half8*)(p + S + g * 8);
            half8 s2 = *(const half8*)(p + 2 * S + g * 8);
            half8 s3 = *(const half8*)(p + 3 * S + g * 8);
            half8 o;
#pragma unroll
            for (int e = 0; e < 8; e++)
                o[e] = (f16)(((float)s0[e] + (float)s1[e]) + ((float)s2[e] + (float)s3[e]));
            *(half8*)&cs[row * SPW + c0 + g * 8] = o;
        }
    }

    floatx4 zz = {0.f, 0.f, 0.f, 0.f};
    floatx4 acc[4] = {zz, zz, zz, zz};

#pragma unroll
    for (int f0 = 0; f0 < F_; f0 += 64) {
        __syncthreads();   // covers cs staging (iter 0) and prior frag reads
#pragma unroll
        for (int rr = 0; rr < 4; rr++) {
            const int o = rr * 64 + wrow;
            const f16* src = Woh + (size_t)o * F_ + f0 + wseg * 16;
            *(float4*)&wtile[o * SP + wseg * 16]     = *(const float4*)(src);
            *(float4*)&wtile[o * SP + wseg * 16 + 8] = *(const float4*)(src + 8);
        }
        __syncthreads();
        half8 a0 = *(const half8*)&cs[l16 * SPW + f0 + quad * 8];
        half8 a1 = *(const half8*)&cs[l16 * SPW + f0 + 32 + quad * 8];
#pragma unroll
        for (int ot = 0; ot < 4; ot++) {
            const int o = wave * 64 + ot * 16 + l16;
            half8 b0 = *(const half8*)&wtile[o * SP + quad * 8];
            half8 b1 = *(const half8*)&wtile[o * SP + 32 + quad * 8];
            acc[ot] = __builtin_amdgcn_mfma_f32_16x16x32_f16(a0, b0, acc[ot], 0, 0, 0);
            acc[ot] = __builtin_amdgcn_mfma_f32_16x16x32_f16(a1, b1, acc[ot], 0, 0, 0);
        }
    }

    // bias + residual
#pragma unroll
    for (int ot = 0; ot < 4; ot++) {
        const int o = wave * 64 + ot * 16 + l16;
        const float bo_ = bo[o];
#pragma unroll
        for (int r = 0; r < 4; r++)
            acc[ot][r] += bo_ + x[(size_t)(n0 + quad * 4 + r) * F_ + o];
    }

    // per-row partial sums over this wave's 64 cols
#pragma unroll
    for (int r = 0; r < 4; r++) {
        float s = (acc[0][r] + acc[1][r]) + (acc[2][r] + acc[3][r]);
        float q = (acc[0][r] * acc[0][r] + acc[1][r] * acc[1][r]) +
                  (acc[2][r] * acc[2][r] + acc[3][r] * acc[3][r]);
        s += __shfl_xor(s, 1); q += __shfl_xor(q, 1);
        s += __shfl_xor(s, 2); q += __shfl_xor(q, 2);
        s += __shfl_xor(s, 4); q += __shfl_xor(q, 4);
        s += __shfl_xor(s, 8); q += __shfl_xor(q, 8);
        if (l16 == 0) { red0[wave][quad * 4 + r] = s; red1[wave][quad * 4 + r] = q; }
    }
    __syncthreads();

#pragma unroll
    for (int r = 0; r < 4; r++) {
        const int rr = quad * 4 + r;
        const float S  = (red0[0][rr] + red0[1][rr]) + (red0[2][rr] + red0[3][rr]);
        const float Q2 = (red1[0][rr] + red1[1][rr]) + (red1[2][rr] + red1[3][rr]);
        const float mu  = S * (1.0f / F_);
        const float var = Q2 * (1.0f / F_) - mu * mu;
        const float inv = rsqrtf(var + 1e-5f);
#pragma unroll
        for (int ot = 0; ot < 4; ot++) {
            const int o = wave * 64 + ot * 16 + l16;
            out[(size_t)(n0 + rr) * F_ + o] =
                (acc[ot][r] - mu) * inv * gamma[o] + beta[o];
        }
    }
}

// ---------------------------------------------------------------------------
extern "C" void kernel_launch(void* const* d_in, const int* in_sizes, int n_in,
                              void* d_out, int out_size, void* d_ws, size_t ws_size,
                              hipStream_t stream)
{
    const float* x     = (const float*)d_in[0];
    const int*   adj   = (const int*)  d_in[1];
    const float* Wq    = (const float*)d_in[2];
    const float* bq    = (const float*)d_in[3];
    const float* Wk    = (const float*)d_in[4];
    const float* bk    = (const float*)d_in[5];
    const float* Wv    = (const float*)d_in[6];
    const float* bv    = (const float*)d_in[7];
    const float* Wo    = (const float*)d_in[8];
    const float* bo    = (const float*)d_in[9];
    const float* gamma = (const float*)d_in[10];
    const float* beta  = (const float*)d_in[11];
    float* out = (float*)d_out;

    float* ws = (float*)d_ws;
    f16*   CTXP = (f16*)(ws);                       // 8M halves
    f16*   Qh   = (f16*)(ws + 4194304);             // 2M halves
    f16*   Kh   = (f16*)(ws + 5242880);
    f16*   Vt   = (f16*)(ws + 6291456);
    u64*   Padj = (u64*)(ws + 7340032);             // 512 KB
    f16*   Woh  = (f16*)(ws + 7471104);             // 64K halves

    hipLaunchKernelGGL(pack_adj, dim3(N_ * 8), dim3(256), 0, stream, adj, Padj);
    hipLaunchKernelGGL(cvt_wo, dim3(64), dim3(256), 0, stream, Wo, Woh);
    hipLaunchKernelGGL(proj_mfma, dim3(BN / 64, H_, 3), dim3(256), 0, stream,
                       x, Wq, Wk, Wv, bq, bk, bv, Qh, Kh, Vt);
    hipLaunchKernelGGL(attn_mfma, dim3(128, H_, B_), dim3(256), 0, stream,
                       Qh, Kh, Vt, Padj, CTXP);
    hipLaunchKernelGGL(out_mfma, dim3(BN / 16), dim3(256), 0, stream,
                       CTXP, x, Woh, bo, gamma, beta, out);
}

// Round 8
// 154.568 us; speedup vs baseline: 1.6151x; 1.0348x over previous
//
#include <hip/hip_runtime.h>
#include <math.h>

#define B_     4
#define N_     2048
#define F_     256
#define H_     4
#define DH     64
#define BN     8192
#define SP     72    // padded f16 stride (64 + 8) -> 144 B
#define SPO    136   // padded f16 stride for proj epilogue (128 + 8)
#define SPW    264   // padded f16 stride for out-kernel ctx rows

#define QSCALE 0.18033688011112042f   // 0.125 * log2(e)
#define CLIP   14.426950408889634f    // 10 * log2(e)

typedef _Float16 f16;
typedef _Float16 half8  __attribute__((ext_vector_type(8)));
typedef _Float16 half4v __attribute__((ext_vector_type(4)));
typedef float    floatx4 __attribute__((ext_vector_type(4)));
typedef unsigned long long u64;

// ---------------------------------------------------------------------------
// Kernel 0: fused prep — pack adj to bits + convert x/Wq/Wk/Wv/Wo to f16.
// blocks [0,16384): pack; then 64 blocks per W; then 2048 blocks for x.
// ---------------------------------------------------------------------------
__global__ __launch_bounds__(256) void prep_kernel(
    const int* __restrict__ adj, u64* __restrict__ P,
    const float* __restrict__ x,  f16* __restrict__ xh,
    const float* __restrict__ Wq, f16* __restrict__ Wqh,
    const float* __restrict__ Wk, f16* __restrict__ Wkh,
    const float* __restrict__ Wv, f16* __restrict__ Wvh,
    const float* __restrict__ Wo, f16* __restrict__ Woh)
{
    const int bid = blockIdx.x;
    if (bid < 16384) {
        const int row   = bid >> 3;
        const int chunk = bid & 7;
        const int wave  = threadIdx.x >> 6, lane = threadIdx.x & 63;
        const int key   = chunk * 256 + wave * 64 + lane;
        u64 m = __ballot(adj[(size_t)row * N_ + key] != 0);
        if (lane == 0) P[(size_t)row * 32 + chunk * 4 + wave] = m;
        return;
    }
    const float* src; f16* dst; int base;
    if      (bid < 16448) { src = Wo; dst = Woh; base = (bid - 16384) * 1024; }
    else if (bid < 16512) { src = Wq; dst = Wqh; base = (bid - 16448) * 1024; }
    else if (bid < 16576) { src = Wk; dst = Wkh; base = (bid - 16512) * 1024; }
    else if (bid < 16640) { src = Wv; dst = Wvh; base = (bid - 16576) * 1024; }
    else                  { src = x;  dst = xh;  base = (bid - 16640) * 1024; }
    const int idx = base + threadIdx.x * 4;
    float4 v = *(const float4*)(src + idx);
    half4v h; h[0] = (f16)v.x; h[1] = (f16)v.y; h[2] = (f16)v.z; h[3] = (f16)v.w;
    *(half4v*)(dst + idx) = h;
}

// ---------------------------------------------------------------------------
// Kernel 1: QKV projection via MFMA, all-f16 inputs.  64n x 128o tile,
// 256 threads; wave owns 16n x 128o (8 MFMA col-tiles).  Q pre-scaled.
// V stored direct-transposed from C-regs.
// ---------------------------------------------------------------------------
__global__ __launch_bounds__(256) void proj_mfma(
    const f16* __restrict__ xh,
    const f16* __restrict__ Wqh, const f16* __restrict__ Wkh, const f16* __restrict__ Wvh,
    const float* __restrict__ bq, const float* __restrict__ bk, const float* __restrict__ bv,
    f16* __restrict__ Qh, f16* __restrict__ Kh, f16* __restrict__ Vt)
{
    const int which = blockIdx.z;
    const f16*   W    = which == 0 ? Wqh : which == 1 ? Wkh : Wvh;
    const float* bias = which == 0 ? bq  : which == 1 ? bk  : bv;

    const int r0 = blockIdx.x * 64;
    const int c0 = blockIdx.y * 128;
    const int tid  = threadIdx.x;
    const int wave = tid >> 6, lane = tid & 63;
    const int quad = lane >> 4, l16 = lane & 15;
    const int row  = tid >> 2, seg  = tid & 3;    // x staging: 64 rows
    const int wrow = tid >> 1, whalf = (tid & 1) * 32;  // W staging: 128 rows

    __shared__ f16 smem[(64 + 128) * SP];
    f16* xs = smem;
    f16* wt = smem + 64 * SP;

    floatx4 zz = {0.f, 0.f, 0.f, 0.f};
    floatx4 acc[8] = {zz, zz, zz, zz, zz, zz, zz, zz};

    for (int f0 = 0; f0 < F_; f0 += 64) {
        const f16* xsrc = xh + (size_t)(r0 + row) * F_ + f0 + seg * 16;
        const f16* wsrc = W  + (size_t)(c0 + wrow) * F_ + f0 + whalf;
        float4 xa0 = *(const float4*)(xsrc),      xa1 = *(const float4*)(xsrc + 8);
        float4 wa0 = *(const float4*)(wsrc),      wa1 = *(const float4*)(wsrc + 8);
        float4 wa2 = *(const float4*)(wsrc + 16), wa3 = *(const float4*)(wsrc + 24);
        __syncthreads();
        *(float4*)&xs[row * SP + seg * 16]      = xa0;
        *(float4*)&xs[row * SP + seg * 16 + 8]  = xa1;
        *(float4*)&wt[wrow * SP + whalf]        = wa0;
        *(float4*)&wt[wrow * SP + whalf + 8]    = wa1;
        *(float4*)&wt[wrow * SP + whalf + 16]   = wa2;
        *(float4*)&wt[wrow * SP + whalf + 24]   = wa3;
        __syncthreads();
        half8 a0 = *(const half8*)&xs[(wave * 16 + l16) * SP + quad * 8];
        half8 a1 = *(const half8*)&xs[(wave * 16 + l16) * SP + 32 + quad * 8];
#pragma unroll
        for (int ot = 0; ot < 8; ot++) {
            half8 b0 = *(const half8*)&wt[(ot * 16 + l16) * SP + quad * 8];
            half8 b1 = *(const half8*)&wt[(ot * 16 + l16) * SP + 32 + quad * 8];
            acc[ot] = __builtin_amdgcn_mfma_f32_16x16x32_f16(a0, b0, acc[ot], 0, 0, 0);
            acc[ot] = __builtin_amdgcn_mfma_f32_16x16x32_f16(a1, b1, acc[ot], 0, 0, 0);
        }
    }

    const int bb = r0 >> 11, nn0 = r0 & (N_ - 1);

    if (which == 2) {
        // direct transposed store: col(l16)=o, rows quad*4+r = contiguous n
#pragma unroll
        for (int ot = 0; ot < 8; ot++) {
            const int o  = c0 + ot * 16 + l16;
            const int hy = o >> 6, dh = o & 63;
            const float bv_ = bias[o];
            half4v h4;
#pragma unroll
            for (int r = 0; r < 4; r++) h4[r] = (f16)(acc[ot][r] + bv_);
            *(half4v*)(Vt + (((size_t)bb * H_ + hy) * DH + dh) * N_
                          + nn0 + wave * 16 + quad * 4) = h4;
        }
    } else {
        const float scl = (which == 0) ? QSCALE : 1.0f;
        f16* dst = which == 0 ? Qh : Kh;
        __syncthreads();
        f16* outb = smem;   // 64 x SPO
#pragma unroll
        for (int ot = 0; ot < 8; ot++) {
            const float bv_ = bias[c0 + ot * 16 + l16];
#pragma unroll
            for (int r = 0; r < 4; r++)
                outb[(wave * 16 + quad * 4 + r) * SPO + ot * 16 + l16] =
                    (f16)((acc[ot][r] + bv_) * scl);
        }
        __syncthreads();
        const int colb = seg * 32;
        const int hh = (c0 + colb) >> 6, dcol = (c0 + colb) & 63;
        f16* g = dst + (((size_t)bb * H_ + hh) * N_ + nn0 + row) * DH + dcol;
#pragma unroll
        for (int k = 0; k < 4; k++)
            *(float4*)(g + k * 8) = *(const float4*)&outb[row * SPO + colb + k * 8];
    }
}

// ---------------------------------------------------------------------------
// Kernel 2: MFMA chunked attention — 512 threads (8 waves), 128 q per block,
// wave owns 16 q (same per-wave structure as the proven R7 kernel).
// K/V staging bytes per tile unchanged -> 2x MFMA per staging.
// ---------------------------------------------------------------------------
__global__ __launch_bounds__(512) void attn_mfma(
    const f16* __restrict__ Qh, const f16* __restrict__ Kh,
    const f16* __restrict__ Vt, const u64* __restrict__ Padj,
    f16* __restrict__ CTXP)
{
    const int nt = blockIdx.x & 15;
    const int sp = blockIdx.x >> 4;        // split 0..3 (2 chunks each)
    const int qb = nt * 128;
    const int h  = blockIdx.y;
    const int b  = blockIdx.z;
    const int bh = b * H_ + h;
    const int tid  = threadIdx.x;
    const int wave = tid >> 6, lane = tid & 63;
    const int quad = lane >> 4, l16 = lane & 15;
    const int qrow = tid >> 2, qseg = tid & 3;     // Q staging: 128 rows
    const int kvr  = tid >> 3, kvs  = tid & 7;     // K/V staging: 64 rows

    __shared__ f16 QPs[128 * SP];  // Q stage, then per-wave P slabs (16 rows each)
    __shared__ f16 Ks[64 * SP];
    __shared__ f16 Vs[64 * SP];    // [d][key]

    {   // stage Q tile [q][dh]: 128 x 64, 16 f16 per thread
        const f16* src = Qh + ((size_t)bh * N_ + qb + qrow) * DH + qseg * 16;
        *(float4*)&QPs[qrow * SP + qseg * 16]     = *(const float4*)(src);
        *(float4*)&QPs[qrow * SP + qseg * 16 + 8] = *(const float4*)(src + 8);
    }
    __syncthreads();
    const half8 qf0 = *(const half8*)&QPs[(wave * 16 + l16) * SP + quad * 8];
    const half8 qf1 = *(const half8*)&QPs[(wave * 16 + l16) * SP + 32 + quad * 8];
    f16* Ps = QPs + wave * 16 * SP;   // wave-private 16 x SP

    const int qglob = qb + wave * 16 + l16;
    const u64* arow = Padj + (size_t)qglob * 32;

    floatx4 zz = {0.f, 0.f, 0.f, 0.f};
    floatx4 ctx_tot[4] = {zz, zz, zz, zz};

    for (int ci = 0; ci < 2; ci++) {
        const int c = sp * 2 + ci;
        floatx4 ctx_ch[4] = {zz, zz, zz, zz};
        float rs_ch = 0.f;

        for (int kt = 0; kt < 4; kt++) {
            const int k0 = c * 256 + kt * 64;
            const f16* ksrc = Kh + ((size_t)bh * N_ + k0 + kvr) * DH + kvs * 8;
            const f16* vsrc = Vt + ((size_t)bh * DH + kvr) * N_ + k0 + kvs * 8;
            float4 ka = *(const float4*)(ksrc);
            float4 va = *(const float4*)(vsrc);
            __syncthreads();
            *(float4*)&Ks[kvr * SP + kvs * 8] = ka;
            *(float4*)&Vs[kvr * SP + kvs * 8] = va;
            __syncthreads();

            const u64 aw = arow[k0 >> 6];
            float rs = 0.f;
#pragma unroll
            for (int m = 0; m < 4; m++) {
                floatx4 sacc = zz;
                half8 a0 = *(const half8*)&Ks[(m * 16 + l16) * SP + quad * 8];
                half8 a1 = *(const half8*)&Ks[(m * 16 + l16) * SP + 32 + quad * 8];
                sacc = __builtin_amdgcn_mfma_f32_16x16x32_f16(a0, qf0, sacc, 0, 0, 0);
                sacc = __builtin_amdgcn_mfma_f32_16x16x32_f16(a1, qf1, sacc, 0, 0, 0);
                const unsigned int nib = (unsigned int)(aw >> (m * 16 + quad * 4)) & 0xFu;
                half4v pv;
#pragma unroll
                for (int r = 0; r < 4; r++) {
                    float sv = fminf(fmaxf(sacc[r], -CLIP), CLIP);
                    sv = ((nib >> r) & 1u) ? sv : -CLIP;
                    const float ev = __builtin_amdgcn_exp2f(sv);
                    rs += ev;
                    pv[r] = (f16)ev;
                }
                *(half4v*)&Ps[l16 * SP + m * 16 + quad * 4] = pv;
            }
            rs += __shfl_xor(rs, 16);
            rs += __shfl_xor(rs, 32);
            rs_ch += rs;

            const half8 p0 = *(const half8*)&Ps[l16 * SP + quad * 8];
            const half8 p1 = *(const half8*)&Ps[l16 * SP + 32 + quad * 8];
#pragma unroll
            for (int m = 0; m < 4; m++) {
                half8 va8 = *(const half8*)&Vs[(m * 16 + l16) * SP + quad * 8];
                half8 vb8 = *(const half8*)&Vs[(m * 16 + l16) * SP + 32 + quad * 8];
                ctx_ch[m] = __builtin_amdgcn_mfma_f32_16x16x32_f16(va8, p0, ctx_ch[m], 0, 0, 0);
                ctx_ch[m] = __builtin_amdgcn_mfma_f32_16x16x32_f16(vb8, p1, ctx_ch[m], 0, 0, 0);
            }
        }

        const float inv = 1.0f / rs_ch;
#pragma unroll
        for (int m = 0; m < 4; m++)
#pragma unroll
            for (int r = 0; r < 4; r++)
                ctx_tot[m][r] += ctx_ch[m][r] * inv;
    }

    f16* dst = CTXP + (((size_t)sp * B_ + b) * N_ + qglob) * F_ + h * DH;
#pragma unroll
    for (int m = 0; m < 4; m++) {
        half4v h4;
#pragma unroll
        for (int r = 0; r < 4; r++) h4[r] = (f16)ctx_tot[m][r];
        *(half4v*)&dst[m * 16 + quad * 4] = h4;
    }
}

// ---------------------------------------------------------------------------
// Kernel 3: fused [sum 4 partials] + [ctx @ Wo^T + bo + x] + LayerNorm.
// Block = 16 rows x 256 cols.  Wo f0-slices staged in LDS.
// ---------------------------------------------------------------------------
__global__ __launch_bounds__(256) void out_mfma(
    const f16* __restrict__ CTXP, const float* __restrict__ x,
    const f16* __restrict__ Woh, const float* __restrict__ bo,
    const float* __restrict__ gamma, const float* __restrict__ beta,
    float* __restrict__ out)
{
    const int n0 = blockIdx.x * 16;
    const int tid  = threadIdx.x;
    const int wave = tid >> 6, lane = tid & 63;
    const int quad = lane >> 4, l16 = lane & 15;
    const int wrow = tid >> 2, wseg = tid & 3;

    __shared__ f16 cs[16 * SPW];
    __shared__ f16 wtile[256 * SP];
    __shared__ float red0[4][16], red1[4][16];

    {   // stage ctx rows: sum 4 f16 split-partials in fp32, store f16
        const int row = tid >> 4, c0 = (tid & 15) * 16;
        const size_t S = (size_t)BN * F_;
        const f16* p = CTXP + (size_t)(n0 + row) * F_ + c0;
#pragma unroll
        for (int g = 0; g < 2; g++) {
            half8 s0 = *(const half8*)(p + g * 8);
            half8 s1 = *(const half8*)(p + S + g * 8);
            half8 s2 = *(const half8*)(p + 2 * S + g * 8);
            half8 s3 = *(const half8*)(p + 3 * S + g * 8);
            half8 o;
#pragma unroll
            for (int e = 0; e < 8; e++)
                o[e] = (f16)(((float)s0[e] + (float)s1[e]) + ((float)s2[e] + (float)s3[e]));
            *(half8*)&cs[row * SPW + c0 + g * 8] = o;
        }
    }

    floatx4 zz = {0.f, 0.f, 0.f, 0.f};
    floatx4 acc[4] = {zz, zz, zz, zz};

#pragma unroll
    for (int f0 = 0; f0 < F_; f0 += 64) {
        __syncthreads();   // covers cs staging (iter 0) and prior frag reads
#pragma unroll
        for (int rr = 0; rr < 4; rr++) {
            const int o = rr * 64 + wrow;
            const f16* src = Woh + (size_t)o * F_ + f0 + wseg * 16;
            *(float4*)&wtile[o * SP + wseg * 16]     = *(const float4*)(src);
            *(float4*)&wtile[o * SP + wseg * 16 + 8] = *(const float4*)(src + 8);
        }
        __syncthreads();
        half8 a0 = *(const half8*)&cs[l16 * SPW + f0 + quad * 8];
        half8 a1 = *(const half8*)&cs[l16 * SPW + f0 + 32 + quad * 8];
#pragma unroll
        for (int ot = 0; ot < 4; ot++) {
            const int o = wave * 64 + ot * 16 + l16;
            half8 b0 = *(const half8*)&wtile[o * SP + quad * 8];
            half8 b1 = *(const half8*)&wtile[o * SP + 32 + quad * 8];
            acc[ot] = __builtin_amdgcn_mfma_f32_16x16x32_f16(a0, b0, acc[ot], 0, 0, 0);
            acc[ot] = __builtin_amdgcn_mfma_f32_16x16x32_f16(a1, b1, acc[ot], 0, 0, 0);
        }
    }

    // bias + residual
#pragma unroll
    for (int ot = 0; ot < 4; ot++) {
        const int o = wave * 64 + ot * 16 + l16;
        const float bo_ = bo[o];
#pragma unroll
        for (int r = 0; r < 4; r++)
            acc[ot][r] += bo_ + x[(size_t)(n0 + quad * 4 + r) * F_ + o];
    }

    // per-row partial sums over this wave's 64 cols
#pragma unroll
    for (int r = 0; r < 4; r++) {
        float s = (acc[0][r] + acc[1][r]) + (acc[2][r] + acc[3][r]);
        float q = (acc[0][r] * acc[0][r] + acc[1][r] * acc[1][r]) +
                  (acc[2][r] * acc[2][r] + acc[3][r] * acc[3][r]);
        s += __shfl_xor(s, 1); q += __shfl_xor(q, 1);
        s += __shfl_xor(s, 2); q += __shfl_xor(q, 2);
        s += __shfl_xor(s, 4); q += __shfl_xor(q, 4);
        s += __shfl_xor(s, 8); q += __shfl_xor(q, 8);
        if (l16 == 0) { red0[wave][quad * 4 + r] = s; red1[wave][quad * 4 + r] = q; }
    }
    __syncthreads();

#pragma unroll
    for (int r = 0; r < 4; r++) {
        const int rr = quad * 4 + r;
        const float S  = (red0[0][rr] + red0[1][rr]) + (red0[2][rr] + red0[3][rr]);
        const float Q2 = (red1[0][rr] + red1[1][rr]) + (red1[2][rr] + red1[3][rr]);
        const float mu  = S * (1.0f / F_);
        const float var = Q2 * (1.0f / F_) - mu * mu;
        const float inv = rsqrtf(var + 1e-5f);
#pragma unroll
        for (int ot = 0; ot < 4; ot++) {
            const int o = wave * 64 + ot * 16 + l16;
            out[(size_t)(n0 + rr) * F_ + o] =
                (acc[ot][r] - mu) * inv * gamma[o] + beta[o];
        }
    }
}

// ---------------------------------------------------------------------------
extern "C" void kernel_launch(void* const* d_in, const int* in_sizes, int n_in,
                              void* d_out, int out_size, void* d_ws, size_t ws_size,
                              hipStream_t stream)
{
    const float* x     = (const float*)d_in[0];
    const int*   adj   = (const int*)  d_in[1];
    const float* Wq    = (const float*)d_in[2];
    const float* bq    = (const float*)d_in[3];
    const float* Wk    = (const float*)d_in[4];
    const float* bk    = (const float*)d_in[5];
    const float* Wv    = (const float*)d_in[6];
    const float* bv    = (const float*)d_in[7];
    const float* Wo    = (const float*)d_in[8];
    const float* bo    = (const float*)d_in[9];
    const float* gamma = (const float*)d_in[10];
    const float* beta  = (const float*)d_in[11];
    float* out = (float*)d_out;

    float* ws = (float*)d_ws;
    f16*   CTXP = (f16*)(ws);                       // 8M halves (4,194,304 fl)
    f16*   Qh   = (f16*)(ws + 4194304);             // 2M halves
    f16*   Kh   = (f16*)(ws + 5242880);
    f16*   Vt   = (f16*)(ws + 6291456);
    u64*   Padj = (u64*)(ws + 7340032);             // 512 KB
    f16*   Woh  = (f16*)(ws + 7471104);             // 64K halves
    // Overlays inside the CTXP region: consumed by proj BEFORE attn writes CTXP.
    f16*   xh   = CTXP;                             // 2M halves
    f16*   Wqh  = (f16*)(ws + 1048576);
    f16*   Wkh  = (f16*)(ws + 1081344);
    f16*   Wvh  = (f16*)(ws + 1114112);

    hipLaunchKernelGGL(prep_kernel, dim3(18688), dim3(256), 0, stream,
                       adj, Padj, x, xh, Wq, Wqh, Wk, Wkh, Wv, Wvh, Wo, Woh);
    hipLaunchKernelGGL(proj_mfma, dim3(BN / 64, 2, 3), dim3(256), 0, stream,
                       xh, Wqh, Wkh, Wvh, bq, bk, bv, Qh, Kh, Vt);
    hipLaunchKernelGGL(attn_mfma, dim3(64, H_, B_), dim3(512), 0, stream,
                       Qh, Kh, Vt, Padj, CTXP);
    hipLaunchKernelGGL(out_mfma, dim3(BN / 16), dim3(256), 0, stream,
                       CTXP, x, Woh, bo, gamma, beta, out);
}